// Round 1
// baseline (3988.820 us; speedup 1.0000x reference)
//
#include <hip/hip_runtime.h>

// DGraphDTA: two GCN branches (mol, protein) + MLP heads + combined head.
// Round 0 baseline: fp32, atomic-scatter aggregation in INPUT feature space
// (agg commutes with x@W since W is shared across nodes), naive matmuls.

static inline int cdiv(int a, int b) { return (a + b - 1) / b; }

// deg[dst] += 1 per edge
__global__ void edge_count_kernel(const int* __restrict__ dst, float* __restrict__ deg, int E) {
    int t = blockIdx.x * blockDim.x + threadIdx.x;
    if (t < E) atomicAdd(&deg[dst[t]], 1.0f);
}

// deg -> rsqrt(deg + 1)  (in place)
__global__ void norm_kernel(float* __restrict__ deg, int N) {
    int t = blockIdx.x * blockDim.x + threadIdx.x;
    if (t < N) deg[t] = rsqrtf(deg[t] + 1.0f);
}

// agg[dst] += x[src] * norm[src], one thread per (edge, feature)
__global__ void scatter_add_kernel(const int* __restrict__ src, const int* __restrict__ dst,
                                   const float* __restrict__ x, const float* __restrict__ norm,
                                   float* __restrict__ agg, int E, int F) {
    int t = blockIdx.x * blockDim.x + threadIdx.x;
    if (t >= E * F) return;
    int e = t / F;
    int j = t - e * F;
    int s = src[e];
    int d = dst[e];
    atomicAdd(&agg[(size_t)d * F + j], x[(size_t)s * F + j] * norm[s]);
}

// agg[n][j] += norm[n] * x[n][j]   (self-loop term, pre-matmul)
__global__ void add_self_kernel(float* __restrict__ agg, const float* __restrict__ x,
                                const float* __restrict__ norm, int N, int F) {
    int t = blockIdx.x * blockDim.x + threadIdx.x;
    if (t >= N * F) return;
    int n = t / F;
    agg[t] += norm[n] * x[t];
}

// out[m][j] = (SCALE? scale[m] : 1) * dot(X[m,:], W[:,j]) + bias[j], optional relu.
// out written at out[m*out_stride + out_off + j] (for concat into xc).
template <bool RELU, bool SCALE>
__global__ void matmul_kernel(const float* __restrict__ X, const float* __restrict__ W,
                              const float* __restrict__ bias, const float* __restrict__ scale,
                              float* __restrict__ out, int M, int K, int N,
                              int out_stride, int out_off) {
    int t = blockIdx.x * blockDim.x + threadIdx.x;
    if (t >= M * N) return;
    int m = t / N;
    int j = t - m * N;
    const float* xr = X + (size_t)m * K;
    const float* wc = W + j;
    float acc = 0.0f;
    for (int k = 0; k < K; ++k) acc = fmaf(xr[k], wc[(size_t)k * N], acc);
    if (SCALE) acc *= scale[m];
    acc += bias[j];
    if (RELU) acc = fmaxf(acc, 0.0f);
    out[(size_t)m * out_stride + out_off + j] = acc;
}

// pool[batch[n]][j] += x[n][j]
__global__ void pool_scatter_kernel(const float* __restrict__ x, const int* __restrict__ batch,
                                    float* __restrict__ pool, int N, int F) {
    int t = blockIdx.x * blockDim.x + threadIdx.x;
    if (t >= N * F) return;
    int n = t / F;
    int j = t - n * F;
    atomicAdd(&pool[(size_t)batch[n] * F + j], x[t]);
}

__global__ void count_kernel(const int* __restrict__ batch, float* __restrict__ cnt, int N) {
    int t = blockIdx.x * blockDim.x + threadIdx.x;
    if (t < N) atomicAdd(&cnt[batch[t]], 1.0f);
}

__global__ void pool_div_kernel(float* __restrict__ pool, const float* __restrict__ cnt, int B, int F) {
    int t = blockIdx.x * blockDim.x + threadIdx.x;
    if (t >= B * F) return;
    int b = t / F;
    pool[t] /= fmaxf(cnt[b], 1.0f);
}

extern "C" void kernel_launch(void* const* d_in, const int* in_sizes, int n_in,
                              void* d_out, int out_size, void* d_ws, size_t ws_size,
                              hipStream_t stream) {
    // ---- inputs ----
    const float* mol_x     = (const float*)d_in[0];
    const int*   mol_ei    = (const int*)  d_in[1];
    const int*   mol_batch = (const int*)  d_in[2];
    const float* pro_x     = (const float*)d_in[3];
    const int*   pro_ei    = (const int*)  d_in[4];
    const int*   pro_batch = (const int*)  d_in[5];
    const float* mw1 = (const float*)d_in[6],  * mb1 = (const float*)d_in[7];
    const float* mw2 = (const float*)d_in[8],  * mb2 = (const float*)d_in[9];
    const float* mw3 = (const float*)d_in[10], * mb3 = (const float*)d_in[11];
    const float* mfw1 = (const float*)d_in[12], * mfb1 = (const float*)d_in[13];
    const float* mfw2 = (const float*)d_in[14], * mfb2 = (const float*)d_in[15];
    const float* pw1 = (const float*)d_in[16], * pb1 = (const float*)d_in[17];
    const float* pw2 = (const float*)d_in[18], * pb2 = (const float*)d_in[19];
    const float* pw3 = (const float*)d_in[20], * pb3 = (const float*)d_in[21];
    const float* pfw1 = (const float*)d_in[22], * pfb1 = (const float*)d_in[23];
    const float* pfw2 = (const float*)d_in[24], * pfb2 = (const float*)d_in[25];
    const float* fc1w = (const float*)d_in[26], * fc1b = (const float*)d_in[27];
    const float* fc2w = (const float*)d_in[28], * fc2b = (const float*)d_in[29];
    const float* outw = (const float*)d_in[30], * outb = (const float*)d_in[31];
    float* out = (float*)d_out;

    // ---- workspace layout (floats). Total ~34.1M floats ~= 136 MB ----
    float* ws_f = (float*)d_ws;
    const size_t SA = (size_t)76800 * 108;  // agg buffer (max N*Fin)
    const size_t SB = (size_t)76800 * 216;  // layer-out buffer (max N*Fout)
    const size_t SC = (size_t)76800 * 108;  // second layer-out buffer
    float* bufA  = ws_f;
    float* bufB  = bufA + SA;
    float* bufC  = bufB + SB;
    float* normb = bufC + SC;            // max N = 76800
    float* pool  = normb + 76800;        // 256 * 312 max
    float* cnt   = pool + 256 * 312;     // 256
    float* fcb   = cnt + 256;            // 256 * 1024
    float* xc    = fcb + 256 * 1024;     // 256 * 256 (concat of both branches)
    float* hb1   = xc + 256 * 256;       // 256 * 1024
    float* hb2   = hb1 + 256 * 1024;     // 256 * 512

    const int BLK = 256;

    // one GCN layer: out = relu(norm * ((scatter(x*norm) + norm*x) @ W) + b)
    auto layer = [&](const float* xin, const float* W, const float* b,
                     int N, int E, const int* ei, int Fin, int Fout,
                     float* agg, float* outp) {
        hipMemsetAsync(agg, 0, (size_t)N * Fin * sizeof(float), stream);
        scatter_add_kernel<<<cdiv(E * Fin, BLK), BLK, 0, stream>>>(ei, ei + E, xin, normb, agg, E, Fin);
        add_self_kernel<<<cdiv(N * Fin, BLK), BLK, 0, stream>>>(agg, xin, normb, N, Fin);
        matmul_kernel<true, true><<<cdiv(N * Fout, BLK), BLK, 0, stream>>>(
            agg, W, b, normb, outp, N, Fin, Fout, Fout, 0);
    };

    auto branch = [&](const float* x0, const int* ei, const int* batch, int N, int E,
                      const float* W1, const float* b1, int F0, int F1,
                      const float* W2, const float* b2, int F2,
                      const float* W3, const float* b3, int F3,
                      const float* fw1, const float* fb1,
                      const float* fw2, const float* fb2, int out_off) {
        // norm = rsqrt(deg_dst + 1)
        hipMemsetAsync(normb, 0, (size_t)N * sizeof(float), stream);
        edge_count_kernel<<<cdiv(E, BLK), BLK, 0, stream>>>(ei + E, normb, E);
        norm_kernel<<<cdiv(N, BLK), BLK, 0, stream>>>(normb, N);
        // three GCN layers (ping-pong: B holds L1 out then L3 out, C holds L2 out)
        layer(x0,   W1, b1, N, E, ei, F0, F1, bufA, bufB);
        layer(bufB, W2, b2, N, E, ei, F1, F2, bufA, bufC);
        layer(bufC, W3, b3, N, E, ei, F2, F3, bufA, bufB);
        // global mean pool
        hipMemsetAsync(pool, 0, (size_t)256 * F3 * sizeof(float), stream);
        hipMemsetAsync(cnt, 0, 256 * sizeof(float), stream);
        pool_scatter_kernel<<<cdiv(N * F3, BLK), BLK, 0, stream>>>(bufB, batch, pool, N, F3);
        count_kernel<<<cdiv(N, BLK), BLK, 0, stream>>>(batch, cnt, N);
        pool_div_kernel<<<cdiv(256 * F3, BLK), BLK, 0, stream>>>(pool, cnt, 256, F3);
        // fc1 (relu) -> fcb [256,1024]
        matmul_kernel<true, false><<<cdiv(256 * 1024, BLK), BLK, 0, stream>>>(
            pool, fw1, fb1, nullptr, fcb, 256, F3, 1024, 1024, 0);
        // fc2 -> xc[:, out_off:out_off+128]
        matmul_kernel<false, false><<<cdiv(256 * 128, BLK), BLK, 0, stream>>>(
            fcb, fw2, fb2, nullptr, xc, 256, 1024, 128, 256, out_off);
    };

    // protein branch (big one) then molecule branch (shares scratch buffers)
    branch(pro_x, pro_ei, pro_batch, 76800, 768000,
           pw1, pb1, 54, 54, pw2, pb2, 108, pw3, pb3, 216,
           pfw1, pfb1, pfw2, pfb2, 128);
    branch(mol_x, mol_ei, mol_batch, 10240, 40960,
           mw1, mb1, 78, 78, mw2, mb2, 156, mw3, mb3, 312,
           mfw1, mfb1, mfw2, mfb2, 0);

    // combined head: xc [256,256] -> 1024 relu -> 512 relu -> 1
    matmul_kernel<true, false><<<cdiv(256 * 1024, BLK), BLK, 0, stream>>>(
        xc, fc1w, fc1b, nullptr, hb1, 256, 256, 1024, 1024, 0);
    matmul_kernel<true, false><<<cdiv(256 * 512, BLK), BLK, 0, stream>>>(
        hb1, fc2w, fc2b, nullptr, hb2, 256, 1024, 512, 512, 0);
    matmul_kernel<false, false><<<1, BLK, 0, stream>>>(
        hb2, outw, outb, nullptr, out, 256, 512, 1, 1, 0);
}

// Round 2
// 1841.027 us; speedup vs baseline: 2.1666x; 2.1666x over previous
//
#include <hip/hip_runtime.h>

// DGraphDTA r2: CSR-gather aggregation (no feature atomics) + LDS-tiled fp32 GEMM.
// Algebra: agg commutes with x@W -> aggregate in input-feature space, then one GEMM.
// y = norm*x precomputed per layer so gather is pure sum (self term = y[n]).

static inline int cdiv(int a, int b) { return (a + b - 1) / b; }

// ---------------- CSR build ----------------

__global__ void deg_kernel(const int* __restrict__ dst, int* __restrict__ deg, int E) {
    int t = blockIdx.x * blockDim.x + threadIdx.x;
    if (t < E) atomicAdd(&deg[dst[t]], 1);
}

__global__ void norm_kernel(const int* __restrict__ deg, float* __restrict__ norm, int N) {
    int t = blockIdx.x * blockDim.x + threadIdx.x;
    if (t < N) norm[t] = rsqrtf((float)deg[t] + 1.0f);
}

// allocate a contiguous region per node via one global cursor (order irrelevant)
__global__ void alloc_rows_kernel(const int* __restrict__ deg, int* __restrict__ row_start,
                                  int* __restrict__ fill_cur, int* __restrict__ cursor, int N) {
    int t = blockIdx.x * blockDim.x + threadIdx.x;
    if (t >= N) return;
    int s = atomicAdd(cursor, deg[t]);
    row_start[t] = s;
    fill_cur[t] = s;
}

__global__ void fill_kernel(const int* __restrict__ src, const int* __restrict__ dst,
                            int* __restrict__ fill_cur, int* __restrict__ edge_src, int E) {
    int t = blockIdx.x * blockDim.x + threadIdx.x;
    if (t >= E) return;
    int p = atomicAdd(&fill_cur[dst[t]], 1);
    edge_src[p] = src[t];
}

// ---------------- GCN aggregation ----------------

// y[t] = norm[t/F] * x[t]
__global__ void scale_copy_kernel(const float* __restrict__ x, const float* __restrict__ norm,
                                  float* __restrict__ y, int N, int F) {
    int t = blockIdx.x * blockDim.x + threadIdx.x;
    if (t >= N * F) return;
    y[t] = norm[t / F] * x[t];
}

__global__ void scale_inplace_kernel(float* __restrict__ x, const float* __restrict__ norm, int N, int F) {
    int t = blockIdx.x * blockDim.x + threadIdx.x;
    if (t >= N * F) return;
    x[t] *= norm[t / F];
}

// agg[n][j] = y[n][j] + sum_{s in nbrs(n)} y[s][j]   (self-loop term included)
__global__ void gather_agg_kernel(const float* __restrict__ y,
                                  const int* __restrict__ row_start, const int* __restrict__ deg,
                                  const int* __restrict__ edge_src,
                                  float* __restrict__ agg, int N, int F) {
    int t = blockIdx.x * blockDim.x + threadIdx.x;
    if (t >= N * F) return;
    int n = t / F;
    int j = t - n * F;
    int rs = row_start[n];
    int d = deg[n];
    float acc = y[(size_t)n * F + j];
    for (int i = 0; i < d; ++i) {
        int s = edge_src[rs + i];
        acc += y[(size_t)s * F + j];
    }
    agg[t] = acc;
}

// ---------------- tiled GEMM ----------------
// out[m][n] = (SCALE? scale[m]:1) * dot(X[m,:], W[:,n]) + bias[n], opt relu,
// written at out[m*out_stride + out_off + n].
template <bool RELU, bool SCALE>
__global__ __launch_bounds__(256) void gemm_kernel(
    const float* __restrict__ X, const float* __restrict__ W,
    const float* __restrict__ bias, const float* __restrict__ scale,
    float* __restrict__ out, int M, int K, int N, int out_stride, int out_off)
{
    constexpr int BM = 64, BN = 64, BK = 16, LDA = BM + 4;  // +4 pad: 2-way max on LDS writes, keeps 16B align
    __shared__ __align__(16) float As[BK * LDA];  // As[k][m] (transposed)
    __shared__ __align__(16) float Bs[BK * BN];   // Bs[k][n]
    const int tid = threadIdx.x;
    const int row0 = blockIdx.y * BM, col0 = blockIdx.x * BN;
    const int tx = tid & 15, ty = tid >> 4;

    float acc[4][4] = {};

    const int a_lr = tid >> 4;   // row within pass (0..15)
    const int a_lk = tid & 15;   // k
    const int b_lc = tid & 63;   // col
    const int b_lk = tid >> 6;   // 0..3

    for (int k0 = 0; k0 < K; k0 += BK) {
#pragma unroll
        for (int p = 0; p < 4; ++p) {
            int r = a_lr + p * 16;
            int gm = row0 + r, gk = k0 + a_lk;
            As[a_lk * LDA + r] = (gm < M && gk < K) ? X[(size_t)gm * K + gk] : 0.0f;
        }
#pragma unroll
        for (int p = 0; p < 4; ++p) {
            int kk = b_lk + p * 4;
            int gk = k0 + kk, gn = col0 + b_lc;
            Bs[kk * BN + b_lc] = (gk < K && gn < N) ? W[(size_t)gk * N + gn] : 0.0f;
        }
        __syncthreads();
#pragma unroll
        for (int k = 0; k < BK; ++k) {
            const float4 a4 = *reinterpret_cast<const float4*>(&As[k * LDA + ty * 4]);
            const float4 b4 = *reinterpret_cast<const float4*>(&Bs[k * BN + tx * 4]);
            const float av[4] = {a4.x, a4.y, a4.z, a4.w};
            const float bv[4] = {b4.x, b4.y, b4.z, b4.w};
#pragma unroll
            for (int i = 0; i < 4; ++i)
#pragma unroll
                for (int j = 0; j < 4; ++j)
                    acc[i][j] = fmaf(av[i], bv[j], acc[i][j]);
        }
        __syncthreads();
    }

#pragma unroll
    for (int i = 0; i < 4; ++i) {
        int gm = row0 + ty * 4 + i;
        if (gm >= M) continue;
        float sc = SCALE ? scale[gm] : 1.0f;
#pragma unroll
        for (int j = 0; j < 4; ++j) {
            int gn = col0 + tx * 4 + j;
            if (gn >= N) continue;
            float v = acc[i][j];
            if (SCALE) v *= sc;
            v += bias[gn];
            if (RELU) v = fmaxf(v, 0.0f);
            out[(size_t)gm * out_stride + out_off + gn] = v;
        }
    }
}

// naive matmul for the tiny final layer (N=1)
__global__ void matvec_kernel(const float* __restrict__ X, const float* __restrict__ W,
                              const float* __restrict__ bias, float* __restrict__ out, int M, int K) {
    int m = blockIdx.x * blockDim.x + threadIdx.x;
    if (m >= M) return;
    const float* xr = X + (size_t)m * K;
    float acc = 0.0f;
    for (int k = 0; k < K; ++k) acc = fmaf(xr[k], W[k], acc);
    out[m] = acc + bias[0];
}

// ---------------- pooling (gather; batch is sorted -> contiguous ranges) ----------------

__global__ void graph_bounds_kernel(const int* __restrict__ batch, int* __restrict__ gstart,
                                    int* __restrict__ gcnt, int N) {
    int t = blockIdx.x * blockDim.x + threadIdx.x;
    if (t >= N) return;
    int b = batch[t];
    atomicMin(&gstart[b], t);
    atomicAdd(&gcnt[b], 1);
}

__global__ void pool_gather_kernel(const float* __restrict__ x, const int* __restrict__ gstart,
                                   const int* __restrict__ gcnt, float* __restrict__ pool, int B, int F) {
    int t = blockIdx.x * blockDim.x + threadIdx.x;
    if (t >= B * F) return;
    int g = t / F;
    int j = t - g * F;
    int s = gstart[g];
    int c = gcnt[g];
    float acc = 0.0f;
    for (int i = 0; i < c; ++i) acc += x[(size_t)(s + i) * F + j];
    pool[t] = acc / (float)max(c, 1);
}

extern "C" void kernel_launch(void* const* d_in, const int* in_sizes, int n_in,
                              void* d_out, int out_size, void* d_ws, size_t ws_size,
                              hipStream_t stream) {
    const float* mol_x     = (const float*)d_in[0];
    const int*   mol_ei    = (const int*)  d_in[1];
    const int*   mol_batch = (const int*)  d_in[2];
    const float* pro_x     = (const float*)d_in[3];
    const int*   pro_ei    = (const int*)  d_in[4];
    const int*   pro_batch = (const int*)  d_in[5];
    const float* mw1 = (const float*)d_in[6],  * mb1 = (const float*)d_in[7];
    const float* mw2 = (const float*)d_in[8],  * mb2 = (const float*)d_in[9];
    const float* mw3 = (const float*)d_in[10], * mb3 = (const float*)d_in[11];
    const float* mfw1 = (const float*)d_in[12], * mfb1 = (const float*)d_in[13];
    const float* mfw2 = (const float*)d_in[14], * mfb2 = (const float*)d_in[15];
    const float* pw1 = (const float*)d_in[16], * pb1 = (const float*)d_in[17];
    const float* pw2 = (const float*)d_in[18], * pb2 = (const float*)d_in[19];
    const float* pw3 = (const float*)d_in[20], * pb3 = (const float*)d_in[21];
    const float* pfw1 = (const float*)d_in[22], * pfb1 = (const float*)d_in[23];
    const float* pfw2 = (const float*)d_in[24], * pfb2 = (const float*)d_in[25];
    const float* fc1w = (const float*)d_in[26], * fc1b = (const float*)d_in[27];
    const float* fc2w = (const float*)d_in[28], * fc2b = (const float*)d_in[29];
    const float* outw = (const float*)d_in[30], * outb = (const float*)d_in[31];
    float* out = (float*)d_out;

    // ---- workspace layout ----
    const int NP = 76800, EP = 768000;
    const int NM = 10240, EM = 40960;
    float* P = (float*)d_ws;                  // 76800*216
    float* Q = P + (size_t)NP * 216;          // 76800*108
    float* R = Q + (size_t)NP * 108;          // 76800*108
    float* normb = R + (size_t)NP * 108;      // 76800
    float* pool  = normb + NP;                // 256*312
    float* fcb   = pool + 256 * 312;          // 256*1024
    float* xc    = fcb + 256 * 1024;          // 256*256
    float* hb1   = xc + 256 * 256;            // 256*1024
    float* hb2   = hb1 + 256 * 1024;          // 256*512
    int* deg_i    = (int*)(hb2 + 256 * 512);  // 76800
    int* row_start= deg_i + NP;               // 76800
    int* fill_cur = row_start + NP;           // 76800
    int* edge_src = fill_cur + NP;            // 768000
    int* cursor   = edge_src + EP;            // 64 (pad)
    int* gstart   = cursor + 64;              // 256
    int* gcnt     = gstart + 256;             // 256

    const int BLK = 256;

    auto gcn_layer = [&](const float* y /*pre-scaled*/, float* agg, float* outp,
                         const float* W, const float* b, int N, int Fin, int Fout) {
        gather_agg_kernel<<<cdiv(N * Fin, BLK), BLK, 0, stream>>>(y, row_start, deg_i, edge_src, agg, N, Fin);
        dim3 grid(cdiv(Fout, 64), cdiv(N, 64));
        gemm_kernel<true, true><<<grid, 256, 0, stream>>>(agg, W, b, normb, outp, N, Fin, Fout, Fout, 0);
    };

    auto branch = [&](const float* x0, const int* ei, const int* batch, int N, int E,
                      const float* W1, const float* b1, int F0, int F1,
                      const float* W2, const float* b2, int F2,
                      const float* W3, const float* b3, int F3,
                      const float* fw1, const float* fb1,
                      const float* fw2, const float* fb2, int out_off) {
        // CSR build + norm
        hipMemsetAsync(deg_i, 0, N * sizeof(int), stream);
        hipMemsetAsync(cursor, 0, sizeof(int), stream);
        deg_kernel<<<cdiv(E, BLK), BLK, 0, stream>>>(ei + E, deg_i, E);
        norm_kernel<<<cdiv(N, BLK), BLK, 0, stream>>>(deg_i, normb, N);
        alloc_rows_kernel<<<cdiv(N, BLK), BLK, 0, stream>>>(deg_i, row_start, fill_cur, cursor, N);
        fill_kernel<<<cdiv(E, BLK), BLK, 0, stream>>>(ei, ei + E, fill_cur, edge_src, E);
        // graph ranges for pooling
        hipMemsetAsync(gstart, 0x7f, 256 * sizeof(int), stream);
        hipMemsetAsync(gcnt, 0, 256 * sizeof(int), stream);
        graph_bounds_kernel<<<cdiv(N, BLK), BLK, 0, stream>>>(batch, gstart, gcnt, N);

        // L1: y=scale(x0)->Q ; agg Q->R ; gemm R->P
        scale_copy_kernel<<<cdiv(N * F0, BLK), BLK, 0, stream>>>(x0, normb, Q, N, F0);
        gcn_layer(Q, R, P, W1, b1, N, F0, F1);
        // L2: scale P in place ; agg P->Q ; gemm Q->R
        scale_inplace_kernel<<<cdiv(N * F1, BLK), BLK, 0, stream>>>(P, normb, N, F1);
        gcn_layer(P, Q, R, W2, b2, N, F1, F2);
        // L3: scale R in place ; agg R->Q ; gemm Q->P
        scale_inplace_kernel<<<cdiv(N * F2, BLK), BLK, 0, stream>>>(R, normb, N, F2);
        gcn_layer(R, Q, P, W3, b3, N, F2, F3);

        // mean pool (gather)
        pool_gather_kernel<<<cdiv(256 * F3, BLK), BLK, 0, stream>>>(P, gstart, gcnt, pool, 256, F3);
        // fc1 relu -> fcb [256,1024]
        {
            dim3 grid(cdiv(1024, 64), cdiv(256, 64));
            gemm_kernel<true, false><<<grid, 256, 0, stream>>>(pool, fw1, fb1, nullptr, fcb, 256, F3, 1024, 1024, 0);
        }
        // fc2 -> xc[:, out_off:+128]
        {
            dim3 grid(cdiv(128, 64), cdiv(256, 64));
            gemm_kernel<false, false><<<grid, 256, 0, stream>>>(fcb, fw2, fb2, nullptr, xc, 256, 1024, 128, 256, out_off);
        }
    };

    branch(pro_x, pro_ei, pro_batch, NP, EP,
           pw1, pb1, 54, 54, pw2, pb2, 108, pw3, pb3, 216,
           pfw1, pfb1, pfw2, pfb2, 128);
    branch(mol_x, mol_ei, mol_batch, NM, EM,
           mw1, mb1, 78, 78, mw2, mb2, 156, mw3, mb3, 312,
           mfw1, mfb1, mfw2, mfb2, 0);

    // combined head
    {
        dim3 grid(cdiv(1024, 64), cdiv(256, 64));
        gemm_kernel<true, false><<<grid, 256, 0, stream>>>(xc, fc1w, fc1b, nullptr, hb1, 256, 256, 1024, 1024, 0);
    }
    {
        dim3 grid(cdiv(512, 64), cdiv(256, 64));
        gemm_kernel<true, false><<<grid, 256, 0, stream>>>(hb1, fc2w, fc2b, nullptr, hb2, 256, 1024, 512, 512, 0);
    }
    matvec_kernel<<<1, 256, 0, stream>>>(hb2, outw, outb, out, 256, 512);
}

// Round 3
// 1552.038 us; speedup vs baseline: 2.5701x; 1.1862x over previous
//
#include <hip/hip_runtime.h>

// DGraphDTA r3: CSR-gather aggregation + tiled GEMM for node-dim matmuls +
// dedicated high-TLP fc_kernel for all M=256 FC layers (r2's 64x64-tile GEMM
// was 1.4% occupancy / latency-bound at M=256: 32 blocks, 64 serial k-steps).

static inline int cdiv(int a, int b) { return (a + b - 1) / b; }

// ---------------- CSR build ----------------

__global__ void deg_kernel(const int* __restrict__ dst, int* __restrict__ deg, int E) {
    int t = blockIdx.x * blockDim.x + threadIdx.x;
    if (t < E) atomicAdd(&deg[dst[t]], 1);
}

__global__ void norm_kernel(const int* __restrict__ deg, float* __restrict__ norm, int N) {
    int t = blockIdx.x * blockDim.x + threadIdx.x;
    if (t < N) norm[t] = rsqrtf((float)deg[t] + 1.0f);
}

// allocate a contiguous region per node via one global cursor (order irrelevant)
__global__ void alloc_rows_kernel(const int* __restrict__ deg, int* __restrict__ row_start,
                                  int* __restrict__ fill_cur, int* __restrict__ cursor, int N) {
    int t = blockIdx.x * blockDim.x + threadIdx.x;
    if (t >= N) return;
    int s = atomicAdd(cursor, deg[t]);
    row_start[t] = s;
    fill_cur[t] = s;
}

__global__ void fill_kernel(const int* __restrict__ src, const int* __restrict__ dst,
                            int* __restrict__ fill_cur, int* __restrict__ edge_src, int E) {
    int t = blockIdx.x * blockDim.x + threadIdx.x;
    if (t >= E) return;
    int p = atomicAdd(&fill_cur[dst[t]], 1);
    edge_src[p] = src[t];
}

// ---------------- GCN aggregation ----------------

__global__ void scale_copy_kernel(const float* __restrict__ x, const float* __restrict__ norm,
                                  float* __restrict__ y, int N, int F) {
    int t = blockIdx.x * blockDim.x + threadIdx.x;
    if (t >= N * F) return;
    y[t] = norm[t / F] * x[t];
}

__global__ void scale_inplace_kernel(float* __restrict__ x, const float* __restrict__ norm, int N, int F) {
    int t = blockIdx.x * blockDim.x + threadIdx.x;
    if (t >= N * F) return;
    x[t] *= norm[t / F];
}

// agg[n][j] = y[n][j] + sum_{s in nbrs(n)} y[s][j]   (self-loop term included)
__global__ void gather_agg_kernel(const float* __restrict__ y,
                                  const int* __restrict__ row_start, const int* __restrict__ deg,
                                  const int* __restrict__ edge_src,
                                  float* __restrict__ agg, int N, int F) {
    int t = blockIdx.x * blockDim.x + threadIdx.x;
    if (t >= N * F) return;
    int n = t / F;
    int j = t - n * F;
    int rs = row_start[n];
    int d = deg[n];
    float acc = y[(size_t)n * F + j];
    for (int i = 0; i < d; ++i) {
        int s = edge_src[rs + i];
        acc += y[(size_t)s * F + j];
    }
    agg[t] = acc;
}

// ---------------- tiled GEMM (node-dim: M = 76800 / 10240) ----------------
template <bool RELU, bool SCALE>
__global__ __launch_bounds__(256) void gemm_kernel(
    const float* __restrict__ X, const float* __restrict__ W,
    const float* __restrict__ bias, const float* __restrict__ scale,
    float* __restrict__ out, int M, int K, int N, int out_stride, int out_off)
{
    constexpr int BM = 64, BN = 64, BK = 16, LDA = BM + 4;
    __shared__ __align__(16) float As[BK * LDA];  // As[k][m] (transposed)
    __shared__ __align__(16) float Bs[BK * BN];   // Bs[k][n]
    const int tid = threadIdx.x;
    const int row0 = blockIdx.y * BM, col0 = blockIdx.x * BN;
    const int tx = tid & 15, ty = tid >> 4;

    float acc[4][4] = {};

    const int a_lr = tid >> 4;   // row within pass (0..15)
    const int a_lk = tid & 15;   // k
    const int b_lc = tid & 63;   // col
    const int b_lk = tid >> 6;   // 0..3

    for (int k0 = 0; k0 < K; k0 += BK) {
#pragma unroll
        for (int p = 0; p < 4; ++p) {
            int r = a_lr + p * 16;
            int gm = row0 + r, gk = k0 + a_lk;
            As[a_lk * LDA + r] = (gm < M && gk < K) ? X[(size_t)gm * K + gk] : 0.0f;
        }
#pragma unroll
        for (int p = 0; p < 4; ++p) {
            int kk = b_lk + p * 4;
            int gk = k0 + kk, gn = col0 + b_lc;
            Bs[kk * BN + b_lc] = (gk < K && gn < N) ? W[(size_t)gk * N + gn] : 0.0f;
        }
        __syncthreads();
#pragma unroll
        for (int k = 0; k < BK; ++k) {
            const float4 a4 = *reinterpret_cast<const float4*>(&As[k * LDA + ty * 4]);
            const float4 b4 = *reinterpret_cast<const float4*>(&Bs[k * BN + tx * 4]);
            const float av[4] = {a4.x, a4.y, a4.z, a4.w};
            const float bv[4] = {b4.x, b4.y, b4.z, b4.w};
#pragma unroll
            for (int i = 0; i < 4; ++i)
#pragma unroll
                for (int j = 0; j < 4; ++j)
                    acc[i][j] = fmaf(av[i], bv[j], acc[i][j]);
        }
        __syncthreads();
    }

#pragma unroll
    for (int i = 0; i < 4; ++i) {
        int gm = row0 + ty * 4 + i;
        if (gm >= M) continue;
        float sc = SCALE ? scale[gm] : 1.0f;
#pragma unroll
        for (int j = 0; j < 4; ++j) {
            int gn = col0 + tx * 4 + j;
            if (gn >= N) continue;
            float v = acc[i][j];
            if (SCALE) v *= sc;
            v += bias[gn];
            if (RELU) v = fmaxf(v, 0.0f);
            out[(size_t)gm * out_stride + out_off + gn] = v;
        }
    }
}

// ---------------- FC kernel (M = 256): high TLP, no K-loop barriers ----------------
// Block = 256 threads = R rows x C cols (R*C=256). X rows staged in LDS once;
// W[k*N+j] coalesced across threads, L2-resident. Grid = (N/C, M/R).
template <bool RELU>
__global__ __launch_bounds__(256) void fc_kernel(
    const float* __restrict__ X, const float* __restrict__ W,
    const float* __restrict__ bias, float* __restrict__ out,
    int M, int K, int N, int C /*cols per block*/, int out_stride, int out_off)
{
    extern __shared__ float Xs[];  // R * K floats
    const int tid = threadIdx.x;
    const int R = 256 / C;
    const int m0 = blockIdx.y * R;
    // stage X rows [m0, m0+R) into LDS
    for (int idx = tid; idx < R * K; idx += 256) {
        int r = idx / K, k = idx - r * K;
        int m = m0 + r;
        Xs[idx] = (m < M) ? X[(size_t)m * K + k] : 0.0f;
    }
    __syncthreads();

    const int r = tid / C;
    const int j = blockIdx.x * C + (tid - r * C);
    const int m = m0 + r;
    if (m >= M || j >= N) return;

    const float* xs = Xs + r * K;
    const float* wc = W + j;
    float acc = 0.0f;
    int k = 0;
    for (; k + 4 <= K; k += 4) {
        acc = fmaf(xs[k + 0], wc[(size_t)(k + 0) * N], acc);
        acc = fmaf(xs[k + 1], wc[(size_t)(k + 1) * N], acc);
        acc = fmaf(xs[k + 2], wc[(size_t)(k + 2) * N], acc);
        acc = fmaf(xs[k + 3], wc[(size_t)(k + 3) * N], acc);
    }
    for (; k < K; ++k) acc = fmaf(xs[k], wc[(size_t)k * N], acc);
    acc += bias[j];
    if (RELU) acc = fmaxf(acc, 0.0f);
    out[(size_t)m * out_stride + out_off + j] = acc;
}

// tiny final layer (N=1)
__global__ void matvec_kernel(const float* __restrict__ X, const float* __restrict__ W,
                              const float* __restrict__ bias, float* __restrict__ out, int M, int K) {
    int m = blockIdx.x * blockDim.x + threadIdx.x;
    if (m >= M) return;
    const float* xr = X + (size_t)m * K;
    float acc = 0.0f;
    for (int k = 0; k < K; ++k) acc = fmaf(xr[k], W[k], acc);
    out[m] = acc + bias[0];
}

// ---------------- pooling (batch sorted -> contiguous ranges) ----------------

__global__ void graph_bounds_kernel(const int* __restrict__ batch, int* __restrict__ gstart,
                                    int* __restrict__ gcnt, int N) {
    int t = blockIdx.x * blockDim.x + threadIdx.x;
    if (t >= N) return;
    int b = batch[t];
    atomicMin(&gstart[b], t);
    atomicAdd(&gcnt[b], 1);
}

__global__ void pool_gather_kernel(const float* __restrict__ x, const int* __restrict__ gstart,
                                   const int* __restrict__ gcnt, float* __restrict__ pool, int B, int F) {
    int t = blockIdx.x * blockDim.x + threadIdx.x;
    if (t >= B * F) return;
    int g = t / F;
    int j = t - g * F;
    int s = gstart[g];
    int c = gcnt[g];
    float acc = 0.0f;
    for (int i = 0; i < c; ++i) acc += x[(size_t)(s + i) * F + j];
    pool[t] = acc / (float)max(c, 1);
}

extern "C" void kernel_launch(void* const* d_in, const int* in_sizes, int n_in,
                              void* d_out, int out_size, void* d_ws, size_t ws_size,
                              hipStream_t stream) {
    const float* mol_x     = (const float*)d_in[0];
    const int*   mol_ei    = (const int*)  d_in[1];
    const int*   mol_batch = (const int*)  d_in[2];
    const float* pro_x     = (const float*)d_in[3];
    const int*   pro_ei    = (const int*)  d_in[4];
    const int*   pro_batch = (const int*)  d_in[5];
    const float* mw1 = (const float*)d_in[6],  * mb1 = (const float*)d_in[7];
    const float* mw2 = (const float*)d_in[8],  * mb2 = (const float*)d_in[9];
    const float* mw3 = (const float*)d_in[10], * mb3 = (const float*)d_in[11];
    const float* mfw1 = (const float*)d_in[12], * mfb1 = (const float*)d_in[13];
    const float* mfw2 = (const float*)d_in[14], * mfb2 = (const float*)d_in[15];
    const float* pw1 = (const float*)d_in[16], * pb1 = (const float*)d_in[17];
    const float* pw2 = (const float*)d_in[18], * pb2 = (const float*)d_in[19];
    const float* pw3 = (const float*)d_in[20], * pb3 = (const float*)d_in[21];
    const float* pfw1 = (const float*)d_in[22], * pfb1 = (const float*)d_in[23];
    const float* pfw2 = (const float*)d_in[24], * pfb2 = (const float*)d_in[25];
    const float* fc1w = (const float*)d_in[26], * fc1b = (const float*)d_in[27];
    const float* fc2w = (const float*)d_in[28], * fc2b = (const float*)d_in[29];
    const float* outw = (const float*)d_in[30], * outb = (const float*)d_in[31];
    float* out = (float*)d_out;

    // ---- workspace layout ----
    const int NP = 76800, EP = 768000;
    const int NM = 10240, EM = 40960;
    float* P = (float*)d_ws;                  // 76800*216
    float* Q = P + (size_t)NP * 216;          // 76800*108
    float* R = Q + (size_t)NP * 108;          // 76800*108
    float* normb = R + (size_t)NP * 108;      // 76800
    float* pool  = normb + NP;                // 256*312
    float* fcb   = pool + 256 * 312;          // 256*1024
    float* xc    = fcb + 256 * 1024;          // 256*256
    float* hb1   = xc + 256 * 256;            // 256*1024
    float* hb2   = hb1 + 256 * 1024;          // 256*512
    int* deg_i    = (int*)(hb2 + 256 * 512);  // 76800
    int* row_start= deg_i + NP;               // 76800
    int* fill_cur = row_start + NP;           // 76800
    int* edge_src = fill_cur + NP;            // 768000
    int* cursor   = edge_src + EP;            // 64 (pad)
    int* gstart   = cursor + 64;              // 256
    int* gcnt     = gstart + 256;             // 256

    const int BLK = 256;

    auto gcn_layer = [&](const float* y /*pre-scaled*/, float* agg, float* outp,
                         const float* W, const float* b, int N, int Fin, int Fout) {
        gather_agg_kernel<<<cdiv(N * Fin, BLK), BLK, 0, stream>>>(y, row_start, deg_i, edge_src, agg, N, Fin);
        dim3 grid(cdiv(Fout, 64), cdiv(N, 64));
        gemm_kernel<true, true><<<grid, 256, 0, stream>>>(agg, W, b, normb, outp, N, Fin, Fout, Fout, 0);
    };

    // fc: out[m, out_off + j] for j in [0,N), m in [0,M=256)
    auto fc = [&](bool relu, const float* X, const float* W, const float* b, float* o,
                  int K, int N, int out_stride, int out_off) {
        int C = (N >= 256) ? 256 : N;     // cols per block (N is 128/512/1024)
        int Rr = 256 / C;
        dim3 grid(cdiv(N, C), cdiv(256, Rr));
        size_t lds = (size_t)Rr * K * sizeof(float);
        if (relu) fc_kernel<true><<<grid, 256, lds, stream>>>(X, W, b, o, 256, K, N, C, out_stride, out_off);
        else      fc_kernel<false><<<grid, 256, lds, stream>>>(X, W, b, o, 256, K, N, C, out_stride, out_off);
    };

    auto branch = [&](const float* x0, const int* ei, const int* batch, int N, int E,
                      const float* W1, const float* b1, int F0, int F1,
                      const float* W2, const float* b2, int F2,
                      const float* W3, const float* b3, int F3,
                      const float* fw1, const float* fb1,
                      const float* fw2, const float* fb2, int out_off) {
        // CSR build + norm
        hipMemsetAsync(deg_i, 0, N * sizeof(int), stream);
        hipMemsetAsync(cursor, 0, sizeof(int), stream);
        deg_kernel<<<cdiv(E, BLK), BLK, 0, stream>>>(ei + E, deg_i, E);
        norm_kernel<<<cdiv(N, BLK), BLK, 0, stream>>>(deg_i, normb, N);
        alloc_rows_kernel<<<cdiv(N, BLK), BLK, 0, stream>>>(deg_i, row_start, fill_cur, cursor, N);
        fill_kernel<<<cdiv(E, BLK), BLK, 0, stream>>>(ei, ei + E, fill_cur, edge_src, E);
        // graph ranges for pooling
        hipMemsetAsync(gstart, 0x7f, 256 * sizeof(int), stream);
        hipMemsetAsync(gcnt, 0, 256 * sizeof(int), stream);
        graph_bounds_kernel<<<cdiv(N, BLK), BLK, 0, stream>>>(batch, gstart, gcnt, N);

        // L1: y=scale(x0)->Q ; agg Q->R ; gemm R->P
        scale_copy_kernel<<<cdiv(N * F0, BLK), BLK, 0, stream>>>(x0, normb, Q, N, F0);
        gcn_layer(Q, R, P, W1, b1, N, F0, F1);
        // L2: scale P in place ; agg P->Q ; gemm Q->R
        scale_inplace_kernel<<<cdiv(N * F1, BLK), BLK, 0, stream>>>(P, normb, N, F1);
        gcn_layer(P, Q, R, W2, b2, N, F1, F2);
        // L3: scale R in place ; agg R->Q ; gemm Q->P
        scale_inplace_kernel<<<cdiv(N * F2, BLK), BLK, 0, stream>>>(R, normb, N, F2);
        gcn_layer(R, Q, P, W3, b3, N, F2, F3);

        // mean pool (gather)
        pool_gather_kernel<<<cdiv(256 * F3, BLK), BLK, 0, stream>>>(P, gstart, gcnt, pool, 256, F3);
        // fc1 relu -> fcb [256,1024] ; fc2 -> xc[:, out_off:+128]
        fc(true,  pool, fw1, fb1, fcb, F3, 1024, 1024, 0);
        fc(false, fcb,  fw2, fb2, xc,  1024, 128, 256, out_off);
    };

    branch(pro_x, pro_ei, pro_batch, NP, EP,
           pw1, pb1, 54, 54, pw2, pb2, 108, pw3, pb3, 216,
           pfw1, pfb1, pfw2, pfb2, 128);
    branch(mol_x, mol_ei, mol_batch, NM, EM,
           mw1, mb1, 78, 78, mw2, mb2, 156, mw3, mb3, 312,
           mfw1, mfb1, mfw2, mfb2, 0);

    // combined head
    fc(true, xc,  fc1w, fc1b, hb1, 256, 1024, 1024, 0);
    fc(true, hb1, fc2w, fc2b, hb2, 1024, 512, 512, 0);
    matvec_kernel<<<1, 256, 0, stream>>>(hb2, outw, outb, out, 256, 512);
}

// Round 4
// 1241.116 us; speedup vs baseline: 3.2139x; 1.2505x over previous
//
#include <hip/hip_runtime.h>

// DGraphDTA r4: vectorized (float4/float2) CSR-gather with fused norm-scaling,
// tiled GEMM for node-dim matmuls, high-TLP fc_kernel for M=256 FC layers.
// r3 evidence: pro L3 gather = 139us @ 4B/lane scalar gathers, VALU 16%, HBM 23%
// -> issue/latency bound; 16B/lane cuts load-instruction count 4x.

static inline int cdiv(int a, int b) { return (a + b - 1) / b; }

// ---------------- CSR build ----------------

__global__ void deg_kernel(const int* __restrict__ dst, int* __restrict__ deg, int E) {
    int t = blockIdx.x * blockDim.x + threadIdx.x;
    if (t < E) atomicAdd(&deg[dst[t]], 1);
}

__global__ void norm_kernel(const int* __restrict__ deg, float* __restrict__ norm, int N) {
    int t = blockIdx.x * blockDim.x + threadIdx.x;
    if (t < N) norm[t] = rsqrtf((float)deg[t] + 1.0f);
}

__global__ void alloc_rows_kernel(const int* __restrict__ deg, int* __restrict__ row_start,
                                  int* __restrict__ fill_cur, int* __restrict__ cursor, int N) {
    int t = blockIdx.x * blockDim.x + threadIdx.x;
    if (t >= N) return;
    int s = atomicAdd(cursor, deg[t]);
    row_start[t] = s;
    fill_cur[t] = s;
}

__global__ void fill_kernel(const int* __restrict__ src, const int* __restrict__ dst,
                            int* __restrict__ fill_cur, int* __restrict__ edge_src, int E) {
    int t = blockIdx.x * blockDim.x + threadIdx.x;
    if (t >= E) return;
    int p = atomicAdd(&fill_cur[dst[t]], 1);
    edge_src[p] = src[t];
}

// ---------------- vectorized gather-aggregate (norm fused) ----------------
// agg[n] = norm[n]*x[n] + sum_s norm[s]*x[s]  in VT-sized chunks.

__device__ __forceinline__ float4 vmad(float s, float4 a, float4 b) {
    return make_float4(fmaf(s, a.x, b.x), fmaf(s, a.y, b.y), fmaf(s, a.z, b.z), fmaf(s, a.w, b.w));
}
__device__ __forceinline__ float2 vmad(float s, float2 a, float2 b) {
    return make_float2(fmaf(s, a.x, b.x), fmaf(s, a.y, b.y));
}
__device__ __forceinline__ float4 vmul(float s, float4 a) {
    return make_float4(s * a.x, s * a.y, s * a.z, s * a.w);
}
__device__ __forceinline__ float2 vmul(float s, float2 a) {
    return make_float2(s * a.x, s * a.y);
}

template <typename VT>
__global__ __launch_bounds__(256) void gather_agg_kernel(
    const float* __restrict__ x, const float* __restrict__ norm,
    const int* __restrict__ row_start, const int* __restrict__ deg,
    const int* __restrict__ edge_src, float* __restrict__ agg, int N, int Fv)
{
    int t = blockIdx.x * blockDim.x + threadIdx.x;
    if (t >= N * Fv) return;
    int n = t / Fv;
    int jv = t - n * Fv;
    const VT* xv = reinterpret_cast<const VT*>(x);
    VT* aggv = reinterpret_cast<VT*>(agg);

    VT acc = vmul(norm[n], xv[(size_t)n * Fv + jv]);
    int rs = row_start[n];
    int d = deg[n];
    const int* es = edge_src + rs;
    int i = 0;
    for (; i + 2 <= d; i += 2) {
        int s0 = es[i], s1 = es[i + 1];
        float n0 = norm[s0], n1 = norm[s1];
        VT v0 = xv[(size_t)s0 * Fv + jv];
        VT v1 = xv[(size_t)s1 * Fv + jv];
        acc = vmad(n0, v0, acc);
        acc = vmad(n1, v1, acc);
    }
    if (i < d) {
        int s0 = es[i];
        acc = vmad(norm[s0], xv[(size_t)s0 * Fv + jv], acc);
    }
    aggv[t] = acc;
}

// ---------------- tiled GEMM (node-dim: M = 76800 / 10240) ----------------
template <bool RELU, bool SCALE>
__global__ __launch_bounds__(256) void gemm_kernel(
    const float* __restrict__ X, const float* __restrict__ W,
    const float* __restrict__ bias, const float* __restrict__ scale,
    float* __restrict__ out, int M, int K, int N, int out_stride, int out_off)
{
    constexpr int BM = 64, BN = 64, BK = 16, LDA = BM + 4;
    __shared__ __align__(16) float As[BK * LDA];  // As[k][m] (transposed)
    __shared__ __align__(16) float Bs[BK * BN];   // Bs[k][n]
    const int tid = threadIdx.x;
    const int row0 = blockIdx.y * BM, col0 = blockIdx.x * BN;
    const int tx = tid & 15, ty = tid >> 4;

    float acc[4][4] = {};

    const int a_lr = tid >> 4;
    const int a_lk = tid & 15;
    const int b_lc = tid & 63;
    const int b_lk = tid >> 6;

    for (int k0 = 0; k0 < K; k0 += BK) {
#pragma unroll
        for (int p = 0; p < 4; ++p) {
            int r = a_lr + p * 16;
            int gm = row0 + r, gk = k0 + a_lk;
            As[a_lk * LDA + r] = (gm < M && gk < K) ? X[(size_t)gm * K + gk] : 0.0f;
        }
#pragma unroll
        for (int p = 0; p < 4; ++p) {
            int kk = b_lk + p * 4;
            int gk = k0 + kk, gn = col0 + b_lc;
            Bs[kk * BN + b_lc] = (gk < K && gn < N) ? W[(size_t)gk * N + gn] : 0.0f;
        }
        __syncthreads();
#pragma unroll
        for (int k = 0; k < BK; ++k) {
            const float4 a4 = *reinterpret_cast<const float4*>(&As[k * LDA + ty * 4]);
            const float4 b4 = *reinterpret_cast<const float4*>(&Bs[k * BN + tx * 4]);
            const float av[4] = {a4.x, a4.y, a4.z, a4.w};
            const float bv[4] = {b4.x, b4.y, b4.z, b4.w};
#pragma unroll
            for (int i = 0; i < 4; ++i)
#pragma unroll
                for (int j = 0; j < 4; ++j)
                    acc[i][j] = fmaf(av[i], bv[j], acc[i][j]);
        }
        __syncthreads();
    }

#pragma unroll
    for (int i = 0; i < 4; ++i) {
        int gm = row0 + ty * 4 + i;
        if (gm >= M) continue;
        float sc = SCALE ? scale[gm] : 1.0f;
#pragma unroll
        for (int j = 0; j < 4; ++j) {
            int gn = col0 + tx * 4 + j;
            if (gn >= N) continue;
            float v = acc[i][j];
            if (SCALE) v *= sc;
            v += bias[gn];
            if (RELU) v = fmaxf(v, 0.0f);
            out[(size_t)gm * out_stride + out_off + gn] = v;
        }
    }
}

// ---------------- FC kernel (M = 256) ----------------
template <bool RELU>
__global__ __launch_bounds__(256) void fc_kernel(
    const float* __restrict__ X, const float* __restrict__ W,
    const float* __restrict__ bias, float* __restrict__ out,
    int M, int K, int N, int C, int out_stride, int out_off)
{
    extern __shared__ float Xs[];  // R * K floats
    const int tid = threadIdx.x;
    const int R = 256 / C;
    const int m0 = blockIdx.y * R;
    for (int idx = tid; idx < R * K; idx += 256) {
        int r = idx / K, k = idx - r * K;
        int m = m0 + r;
        Xs[idx] = (m < M) ? X[(size_t)m * K + k] : 0.0f;
    }
    __syncthreads();

    const int r = tid / C;
    const int j = blockIdx.x * C + (tid - r * C);
    const int m = m0 + r;
    if (m >= M || j >= N) return;

    const float* xs = Xs + r * K;
    const float* wc = W + j;
    float acc = 0.0f;
    int k = 0;
    for (; k + 4 <= K; k += 4) {
        acc = fmaf(xs[k + 0], wc[(size_t)(k + 0) * N], acc);
        acc = fmaf(xs[k + 1], wc[(size_t)(k + 1) * N], acc);
        acc = fmaf(xs[k + 2], wc[(size_t)(k + 2) * N], acc);
        acc = fmaf(xs[k + 3], wc[(size_t)(k + 3) * N], acc);
    }
    for (; k < K; ++k) acc = fmaf(xs[k], wc[(size_t)k * N], acc);
    acc += bias[j];
    if (RELU) acc = fmaxf(acc, 0.0f);
    out[(size_t)m * out_stride + out_off + j] = acc;
}

__global__ void matvec_kernel(const float* __restrict__ X, const float* __restrict__ W,
                              const float* __restrict__ bias, float* __restrict__ out, int M, int K) {
    int m = blockIdx.x * blockDim.x + threadIdx.x;
    if (m >= M) return;
    const float* xr = X + (size_t)m * K;
    float acc = 0.0f;
    for (int k = 0; k < K; ++k) acc = fmaf(xr[k], W[k], acc);
    out[m] = acc + bias[0];
}

// ---------------- pooling (batch sorted -> contiguous ranges) ----------------

__global__ void graph_bounds_kernel(const int* __restrict__ batch, int* __restrict__ gstart,
                                    int* __restrict__ gcnt, int N) {
    int t = blockIdx.x * blockDim.x + threadIdx.x;
    if (t >= N) return;
    int b = batch[t];
    atomicMin(&gstart[b], t);
    atomicAdd(&gcnt[b], 1);
}

__global__ void pool_gather_kernel(const float* __restrict__ x, const int* __restrict__ gstart,
                                   const int* __restrict__ gcnt, float* __restrict__ pool, int B, int F) {
    int t = blockIdx.x * blockDim.x + threadIdx.x;
    if (t >= B * F) return;
    int g = t / F;
    int j = t - g * F;
    int s = gstart[g];
    int c = gcnt[g];
    float acc = 0.0f;
    for (int i = 0; i < c; ++i) acc += x[(size_t)(s + i) * F + j];
    pool[t] = acc / (float)max(c, 1);
}

extern "C" void kernel_launch(void* const* d_in, const int* in_sizes, int n_in,
                              void* d_out, int out_size, void* d_ws, size_t ws_size,
                              hipStream_t stream) {
    const float* mol_x     = (const float*)d_in[0];
    const int*   mol_ei    = (const int*)  d_in[1];
    const int*   mol_batch = (const int*)  d_in[2];
    const float* pro_x     = (const float*)d_in[3];
    const int*   pro_ei    = (const int*)  d_in[4];
    const int*   pro_batch = (const int*)  d_in[5];
    const float* mw1 = (const float*)d_in[6],  * mb1 = (const float*)d_in[7];
    const float* mw2 = (const float*)d_in[8],  * mb2 = (const float*)d_in[9];
    const float* mw3 = (const float*)d_in[10], * mb3 = (const float*)d_in[11];
    const float* mfw1 = (const float*)d_in[12], * mfb1 = (const float*)d_in[13];
    const float* mfw2 = (const float*)d_in[14], * mfb2 = (const float*)d_in[15];
    const float* pw1 = (const float*)d_in[16], * pb1 = (const float*)d_in[17];
    const float* pw2 = (const float*)d_in[18], * pb2 = (const float*)d_in[19];
    const float* pw3 = (const float*)d_in[20], * pb3 = (const float*)d_in[21];
    const float* pfw1 = (const float*)d_in[22], * pfb1 = (const float*)d_in[23];
    const float* pfw2 = (const float*)d_in[24], * pfb2 = (const float*)d_in[25];
    const float* fc1w = (const float*)d_in[26], * fc1b = (const float*)d_in[27];
    const float* fc2w = (const float*)d_in[28], * fc2b = (const float*)d_in[29];
    const float* outw = (const float*)d_in[30], * outb = (const float*)d_in[31];
    float* out = (float*)d_out;

    // ---- workspace layout ----
    const int NP = 76800, EP = 768000;
    const int NM = 10240, EM = 40960;
    float* P = (float*)d_ws;                  // 76800*216
    float* Q = P + (size_t)NP * 216;          // 76800*108
    float* R = Q + (size_t)NP * 108;          // 76800*108
    float* normb = R + (size_t)NP * 108;      // 76800
    float* pool  = normb + NP;                // 256*312
    float* fcb   = pool + 256 * 312;          // 256*1024
    float* xc    = fcb + 256 * 1024;          // 256*256
    float* hb1   = xc + 256 * 256;            // 256*1024
    float* hb2   = hb1 + 256 * 1024;          // 256*512
    int* deg_i    = (int*)(hb2 + 256 * 512);  // 76800
    int* row_start= deg_i + NP;               // 76800
    int* fill_cur = row_start + NP;           // 76800
    int* edge_src = fill_cur + NP;            // 768000
    int* cursor   = edge_src + EP;            // 64 (pad)
    int* gstart   = cursor + 64;              // 256
    int* gcnt     = gstart + 256;             // 256

    const int BLK = 256;

    // gather (vectorized, norm fused) + gemm (epilogue norm-scale + bias + relu)
    auto gcn_layer = [&](const float* xin, float* agg, float* outp,
                         const float* W, const float* b, int N, int Fin, int Fout) {
        if (Fin % 4 == 0) {
            int Fv = Fin / 4;
            gather_agg_kernel<float4><<<cdiv(N * Fv, BLK), BLK, 0, stream>>>(
                xin, normb, row_start, deg_i, edge_src, agg, N, Fv);
        } else {
            int Fv = Fin / 2;
            gather_agg_kernel<float2><<<cdiv(N * Fv, BLK), BLK, 0, stream>>>(
                xin, normb, row_start, deg_i, edge_src, agg, N, Fv);
        }
        dim3 grid(cdiv(Fout, 64), cdiv(N, 64));
        gemm_kernel<true, true><<<grid, 256, 0, stream>>>(agg, W, b, normb, outp, N, Fin, Fout, Fout, 0);
    };

    auto fc = [&](bool relu, const float* X, const float* W, const float* b, float* o,
                  int K, int N, int out_stride, int out_off) {
        int C = (N >= 256) ? 256 : N;
        int Rr = 256 / C;
        dim3 grid(cdiv(N, C), cdiv(256, Rr));
        size_t lds = (size_t)Rr * K * sizeof(float);
        if (relu) fc_kernel<true><<<grid, 256, lds, stream>>>(X, W, b, o, 256, K, N, C, out_stride, out_off);
        else      fc_kernel<false><<<grid, 256, lds, stream>>>(X, W, b, o, 256, K, N, C, out_stride, out_off);
    };

    auto branch = [&](const float* x0, const int* ei, const int* batch, int N, int E,
                      const float* W1, const float* b1, int F0, int F1,
                      const float* W2, const float* b2, int F2,
                      const float* W3, const float* b3, int F3,
                      const float* fw1, const float* fb1,
                      const float* fw2, const float* fb2, int out_off) {
        // CSR build + norm
        hipMemsetAsync(deg_i, 0, N * sizeof(int), stream);
        hipMemsetAsync(cursor, 0, sizeof(int), stream);
        deg_kernel<<<cdiv(E, BLK), BLK, 0, stream>>>(ei + E, deg_i, E);
        norm_kernel<<<cdiv(N, BLK), BLK, 0, stream>>>(deg_i, normb, N);
        alloc_rows_kernel<<<cdiv(N, BLK), BLK, 0, stream>>>(deg_i, row_start, fill_cur, cursor, N);
        fill_kernel<<<cdiv(E, BLK), BLK, 0, stream>>>(ei, ei + E, fill_cur, edge_src, E);
        // graph ranges for pooling
        hipMemsetAsync(gstart, 0x7f, 256 * sizeof(int), stream);
        hipMemsetAsync(gcnt, 0, 256 * sizeof(int), stream);
        graph_bounds_kernel<<<cdiv(N, BLK), BLK, 0, stream>>>(batch, gstart, gcnt, N);

        // L1: agg(x0)->Q ; gemm Q->P   (P holds F1 out)
        gcn_layer(x0, Q, P, W1, b1, N, F0, F1);
        // L2: agg(P)->Q ; gemm Q->R    (R holds F2 out)
        gcn_layer(P, Q, R, W2, b2, N, F1, F2);
        // L3: agg(R)->Q ; gemm Q->P    (P holds F3 out)
        gcn_layer(R, Q, P, W3, b3, N, F2, F3);

        // mean pool
        pool_gather_kernel<<<cdiv(256 * F3, BLK), BLK, 0, stream>>>(P, gstart, gcnt, pool, 256, F3);
        fc(true,  pool, fw1, fb1, fcb, F3, 1024, 1024, 0);
        fc(false, fcb,  fw2, fb2, xc,  1024, 128, 256, out_off);
    };

    branch(pro_x, pro_ei, pro_batch, NP, EP,
           pw1, pb1, 54, 54, pw2, pb2, 108, pw3, pb3, 216,
           pfw1, pfb1, pfw2, pfb2, 128);
    branch(mol_x, mol_ei, mol_batch, NM, EM,
           mw1, mb1, 78, 78, mw2, mb2, 156, mw3, mb3, 312,
           mfw1, mfb1, mfw2, mfb2, 0);

    // combined head
    fc(true, xc,  fc1w, fc1b, hb1, 256, 1024, 1024, 0);
    fc(true, hb1, fc2w, fc2b, hb2, 1024, 512, 512, 0);
    matvec_kernel<<<1, 256, 0, stream>>>(hb2, outw, outb, out, 256, 512);
}

// Round 6
// 1142.046 us; speedup vs baseline: 3.4927x; 1.0867x over previous
//
#include <hip/hip_runtime.h>

// DGraphDTA r6: r5's split-K FC kernel with the j0-offset store bug fixed
// (r5 wrote all column-blocks to block 0's output range).

static inline int cdiv(int a, int b) { return (a + b - 1) / b; }

// ---------------- CSR build ----------------

__global__ void deg_kernel(const int* __restrict__ dst, int* __restrict__ deg, int E) {
    int t = blockIdx.x * blockDim.x + threadIdx.x;
    if (t < E) atomicAdd(&deg[dst[t]], 1);
}

__global__ void norm_kernel(const int* __restrict__ deg, float* __restrict__ norm, int N) {
    int t = blockIdx.x * blockDim.x + threadIdx.x;
    if (t < N) norm[t] = rsqrtf((float)deg[t] + 1.0f);
}

__global__ void alloc_rows_kernel(const int* __restrict__ deg, int* __restrict__ row_start,
                                  int* __restrict__ fill_cur, int* __restrict__ cursor, int N) {
    int t = blockIdx.x * blockDim.x + threadIdx.x;
    if (t >= N) return;
    int s = atomicAdd(cursor, deg[t]);
    row_start[t] = s;
    fill_cur[t] = s;
}

__global__ void fill_kernel(const int* __restrict__ src, const int* __restrict__ dst,
                            int* __restrict__ fill_cur, int* __restrict__ edge_src, int E) {
    int t = blockIdx.x * blockDim.x + threadIdx.x;
    if (t >= E) return;
    int p = atomicAdd(&fill_cur[dst[t]], 1);
    edge_src[p] = src[t];
}

// ---------------- vectorized gather-aggregate (norm fused) ----------------

__device__ __forceinline__ float4 vmad(float s, float4 a, float4 b) {
    return make_float4(fmaf(s, a.x, b.x), fmaf(s, a.y, b.y), fmaf(s, a.z, b.z), fmaf(s, a.w, b.w));
}
__device__ __forceinline__ float2 vmad(float s, float2 a, float2 b) {
    return make_float2(fmaf(s, a.x, b.x), fmaf(s, a.y, b.y));
}
__device__ __forceinline__ float4 vmul(float s, float4 a) {
    return make_float4(s * a.x, s * a.y, s * a.z, s * a.w);
}
__device__ __forceinline__ float2 vmul(float s, float2 a) {
    return make_float2(s * a.x, s * a.y);
}

template <typename VT>
__global__ __launch_bounds__(256) void gather_agg_kernel(
    const float* __restrict__ x, const float* __restrict__ norm,
    const int* __restrict__ row_start, const int* __restrict__ deg,
    const int* __restrict__ edge_src, float* __restrict__ agg, int N, int Fv)
{
    int t = blockIdx.x * blockDim.x + threadIdx.x;
    if (t >= N * Fv) return;
    int n = t / Fv;
    int jv = t - n * Fv;
    const VT* xv = reinterpret_cast<const VT*>(x);
    VT* aggv = reinterpret_cast<VT*>(agg);

    VT acc = vmul(norm[n], xv[(size_t)n * Fv + jv]);
    int rs = row_start[n];
    int d = deg[n];
    const int* es = edge_src + rs;
    int i = 0;
    for (; i + 2 <= d; i += 2) {
        int s0 = es[i], s1 = es[i + 1];
        float n0 = norm[s0], n1 = norm[s1];
        VT v0 = xv[(size_t)s0 * Fv + jv];
        VT v1 = xv[(size_t)s1 * Fv + jv];
        acc = vmad(n0, v0, acc);
        acc = vmad(n1, v1, acc);
    }
    if (i < d) {
        int s0 = es[i];
        acc = vmad(norm[s0], xv[(size_t)s0 * Fv + jv], acc);
    }
    aggv[t] = acc;
}

// ---------------- tiled GEMM (node-dim: M = 76800 / 10240) ----------------
template <bool RELU, bool SCALE>
__global__ __launch_bounds__(256) void gemm_kernel(
    const float* __restrict__ X, const float* __restrict__ W,
    const float* __restrict__ bias, const float* __restrict__ scale,
    float* __restrict__ out, int M, int K, int N, int out_stride, int out_off)
{
    constexpr int BM = 64, BN = 64, BK = 16, LDA = BM + 4;
    __shared__ __align__(16) float As[BK * LDA];  // As[k][m] (transposed)
    __shared__ __align__(16) float Bs[BK * BN];   // Bs[k][n]
    const int tid = threadIdx.x;
    const int row0 = blockIdx.y * BM, col0 = blockIdx.x * BN;
    const int tx = tid & 15, ty = tid >> 4;

    float acc[4][4] = {};

    const int a_lr = tid >> 4;
    const int a_lk = tid & 15;
    const int b_lc = tid & 63;
    const int b_lk = tid >> 6;

    for (int k0 = 0; k0 < K; k0 += BK) {
#pragma unroll
        for (int p = 0; p < 4; ++p) {
            int r = a_lr + p * 16;
            int gm = row0 + r, gk = k0 + a_lk;
            As[a_lk * LDA + r] = (gm < M && gk < K) ? X[(size_t)gm * K + gk] : 0.0f;
        }
#pragma unroll
        for (int p = 0; p < 4; ++p) {
            int kk = b_lk + p * 4;
            int gk = k0 + kk, gn = col0 + b_lc;
            Bs[kk * BN + b_lc] = (gk < K && gn < N) ? W[(size_t)gk * N + gn] : 0.0f;
        }
        __syncthreads();
#pragma unroll
        for (int k = 0; k < BK; ++k) {
            const float4 a4 = *reinterpret_cast<const float4*>(&As[k * LDA + ty * 4]);
            const float4 b4 = *reinterpret_cast<const float4*>(&Bs[k * BN + tx * 4]);
            const float av[4] = {a4.x, a4.y, a4.z, a4.w};
            const float bv[4] = {b4.x, b4.y, b4.z, b4.w};
#pragma unroll
            for (int i = 0; i < 4; ++i)
#pragma unroll
                for (int j = 0; j < 4; ++j)
                    acc[i][j] = fmaf(av[i], bv[j], acc[i][j]);
        }
        __syncthreads();
    }

#pragma unroll
    for (int i = 0; i < 4; ++i) {
        int gm = row0 + ty * 4 + i;
        if (gm >= M) continue;
        float sc = SCALE ? scale[gm] : 1.0f;
#pragma unroll
        for (int j = 0; j < 4; ++j) {
            int gn = col0 + tx * 4 + j;
            if (gn >= N) continue;
            float v = acc[i][j];
            if (SCALE) v *= sc;
            v += bias[gn];
            if (RELU) v = fmaxf(v, 0.0f);
            out[(size_t)gm * out_stride + out_off + gn] = v;
        }
    }
}

// ---------------- FC kernel v2 (M = 256): split-K + float4 W loads ----------------
// Block = 256 threads = (JT/4 j-groups) x (SK slices). One block computes row m,
// columns [j0, j0+JT). X row in LDS; per-thread float4 W accumulation over K/SK;
// LDS reduction across slices. Grid = (N/JT, M).
template <bool RELU, int JT>
__global__ __launch_bounds__(256) void fc_kernel(
    const float* __restrict__ X, const float* __restrict__ W,
    const float* __restrict__ bias, float* __restrict__ out,
    int K, int N, int out_stride, int out_off)
{
    constexpr int TJ = JT / 4;       // threads along j
    constexpr int SK = 256 / TJ;     // k slices
    extern __shared__ float smem[];  // Xs[K] + red[SK*JT]
    float* Xs = smem;
    float* red = smem + K;

    const int tid = threadIdx.x;
    const int m = blockIdx.y;
    const int j0 = blockIdx.x * JT;

    for (int i = tid; i < K; i += 256) Xs[i] = X[(size_t)m * K + i];
    __syncthreads();

    const int tj = tid % TJ;         // j-group
    const int s  = tid / TJ;         // slice
    const int chunk = (K + SK - 1) / SK;
    const int kb = s * chunk;
    const int ke = min(K, kb + chunk);

    const float4* w4 = reinterpret_cast<const float4*>(W + j0) + tj;  // + k*(N/4)
    const int wstride = N >> 2;

    float4 p = make_float4(0.f, 0.f, 0.f, 0.f);
    for (int k = kb; k < ke; ++k) {
        float xk = Xs[k];
        float4 w = w4[(size_t)k * wstride];
        p = vmad(xk, w, p);
    }
    float* rr = red + s * JT + tj * 4;
    rr[0] = p.x; rr[1] = p.y; rr[2] = p.z; rr[3] = p.w;
    __syncthreads();

    if (tid < JT) {
        float v = 0.f;
#pragma unroll
        for (int ss = 0; ss < SK; ++ss) v += red[ss * JT + tid];
        v += bias[j0 + tid];
        if (RELU) v = fmaxf(v, 0.0f);
        out[(size_t)m * out_stride + out_off + j0 + tid] = v;  // FIX: + j0
    }
}

// final layer: one block per row, 256 threads, LDS tree reduce (K=512)
__global__ __launch_bounds__(256) void matvec_kernel(
    const float* __restrict__ X, const float* __restrict__ W,
    const float* __restrict__ bias, float* __restrict__ out, int K)
{
    __shared__ float red[256];
    const int m = blockIdx.x;
    const int tid = threadIdx.x;
    float acc = 0.f;
    for (int k = tid; k < K; k += 256) acc = fmaf(X[(size_t)m * K + k], W[k], acc);
    red[tid] = acc;
    __syncthreads();
    for (int w = 128; w >= 64; w >>= 1) {
        if (tid < w) red[tid] += red[tid + w];
        __syncthreads();
    }
    if (tid < 64) {
        float v = red[tid];
        for (int off = 32; off > 0; off >>= 1) v += __shfl_down(v, off, 64);
        if (tid == 0) out[m] = v + bias[0];
    }
}

// ---------------- pooling (batch sorted -> contiguous ranges) ----------------

__global__ void graph_bounds_kernel(const int* __restrict__ batch, int* __restrict__ gstart,
                                    int* __restrict__ gcnt, int N) {
    int t = blockIdx.x * blockDim.x + threadIdx.x;
    if (t >= N) return;
    int b = batch[t];
    atomicMin(&gstart[b], t);
    atomicAdd(&gcnt[b], 1);
}

__global__ void pool_gather_kernel(const float* __restrict__ x, const int* __restrict__ gstart,
                                   const int* __restrict__ gcnt, float* __restrict__ pool, int B, int F) {
    int t = blockIdx.x * blockDim.x + threadIdx.x;
    if (t >= B * F) return;
    int g = t / F;
    int j = t - g * F;
    int s = gstart[g];
    int c = gcnt[g];
    float acc = 0.0f;
    for (int i = 0; i < c; ++i) acc += x[(size_t)(s + i) * F + j];
    pool[t] = acc / (float)max(c, 1);
}

extern "C" void kernel_launch(void* const* d_in, const int* in_sizes, int n_in,
                              void* d_out, int out_size, void* d_ws, size_t ws_size,
                              hipStream_t stream) {
    const float* mol_x     = (const float*)d_in[0];
    const int*   mol_ei    = (const int*)  d_in[1];
    const int*   mol_batch = (const int*)  d_in[2];
    const float* pro_x     = (const float*)d_in[3];
    const int*   pro_ei    = (const int*)  d_in[4];
    const int*   pro_batch = (const int*)  d_in[5];
    const float* mw1 = (const float*)d_in[6],  * mb1 = (const float*)d_in[7];
    const float* mw2 = (const float*)d_in[8],  * mb2 = (const float*)d_in[9];
    const float* mw3 = (const float*)d_in[10], * mb3 = (const float*)d_in[11];
    const float* mfw1 = (const float*)d_in[12], * mfb1 = (const float*)d_in[13];
    const float* mfw2 = (const float*)d_in[14], * mfb2 = (const float*)d_in[15];
    const float* pw1 = (const float*)d_in[16], * pb1 = (const float*)d_in[17];
    const float* pw2 = (const float*)d_in[18], * pb2 = (const float*)d_in[19];
    const float* pw3 = (const float*)d_in[20], * pb3 = (const float*)d_in[21];
    const float* pfw1 = (const float*)d_in[22], * pfb1 = (const float*)d_in[23];
    const float* pfw2 = (const float*)d_in[24], * pfb2 = (const float*)d_in[25];
    const float* fc1w = (const float*)d_in[26], * fc1b = (const float*)d_in[27];
    const float* fc2w = (const float*)d_in[28], * fc2b = (const float*)d_in[29];
    const float* outw = (const float*)d_in[30], * outb = (const float*)d_in[31];
    float* out = (float*)d_out;

    // ---- workspace layout ----
    const int NP = 76800, EP = 768000;
    const int NM = 10240, EM = 40960;
    float* P = (float*)d_ws;                  // 76800*216
    float* Q = P + (size_t)NP * 216;          // 76800*108
    float* R = Q + (size_t)NP * 108;          // 76800*108
    float* normb = R + (size_t)NP * 108;      // 76800
    float* pool  = normb + NP;                // 256*312
    float* fcb   = pool + 256 * 312;          // 256*1024
    float* xc    = fcb + 256 * 1024;          // 256*256
    float* hb1   = xc + 256 * 256;            // 256*1024
    float* hb2   = hb1 + 256 * 1024;          // 256*512
    int* deg_i    = (int*)(hb2 + 256 * 512);  // 76800
    int* row_start= deg_i + NP;               // 76800
    int* fill_cur = row_start + NP;           // 76800
    int* edge_src = fill_cur + NP;            // 768000
    int* cursor   = edge_src + EP;            // 64 (pad)
    int* gstart   = cursor + 64;              // 256
    int* gcnt     = gstart + 256;             // 256

    const int BLK = 256;

    auto gcn_layer = [&](const float* xin, float* agg, float* outp,
                         const float* W, const float* b, int N, int Fin, int Fout) {
        if (Fin % 4 == 0) {
            int Fv = Fin / 4;
            gather_agg_kernel<float4><<<cdiv(N * Fv, BLK), BLK, 0, stream>>>(
                xin, normb, row_start, deg_i, edge_src, agg, N, Fv);
        } else {
            int Fv = Fin / 2;
            gather_agg_kernel<float2><<<cdiv(N * Fv, BLK), BLK, 0, stream>>>(
                xin, normb, row_start, deg_i, edge_src, agg, N, Fv);
        }
        dim3 grid(cdiv(Fout, 64), cdiv(N, 64));
        gemm_kernel<true, true><<<grid, 256, 0, stream>>>(agg, W, b, normb, outp, N, Fin, Fout, Fout, 0);
    };

    // FC (M=256): JT=256 for wide N, JT=128 for N=128
    auto fc = [&](bool relu, const float* X, const float* W, const float* b, float* o,
                  int K, int N, int out_stride, int out_off) {
        size_t lds = (size_t)(K + 1024) * sizeof(float);
        if (N % 256 == 0) {
            dim3 grid(N / 256, 256);
            if (relu) fc_kernel<true, 256><<<grid, 256, lds, stream>>>(X, W, b, o, K, N, out_stride, out_off);
            else      fc_kernel<false, 256><<<grid, 256, lds, stream>>>(X, W, b, o, K, N, out_stride, out_off);
        } else {  // N == 128
            dim3 grid(N / 128, 256);
            if (relu) fc_kernel<true, 128><<<grid, 256, lds, stream>>>(X, W, b, o, K, N, out_stride, out_off);
            else      fc_kernel<false, 128><<<grid, 256, lds, stream>>>(X, W, b, o, K, N, out_stride, out_off);
        }
    };

    auto branch = [&](const float* x0, const int* ei, const int* batch, int N, int E,
                      const float* W1, const float* b1, int F0, int F1,
                      const float* W2, const float* b2, int F2,
                      const float* W3, const float* b3, int F3,
                      const float* fw1, const float* fb1,
                      const float* fw2, const float* fb2, int out_off) {
        // CSR build + norm
        hipMemsetAsync(deg_i, 0, N * sizeof(int), stream);
        hipMemsetAsync(cursor, 0, sizeof(int), stream);
        deg_kernel<<<cdiv(E, BLK), BLK, 0, stream>>>(ei + E, deg_i, E);
        norm_kernel<<<cdiv(N, BLK), BLK, 0, stream>>>(deg_i, normb, N);
        alloc_rows_kernel<<<cdiv(N, BLK), BLK, 0, stream>>>(deg_i, row_start, fill_cur, cursor, N);
        fill_kernel<<<cdiv(E, BLK), BLK, 0, stream>>>(ei, ei + E, fill_cur, edge_src, E);
        // graph ranges for pooling
        hipMemsetAsync(gstart, 0x7f, 256 * sizeof(int), stream);
        hipMemsetAsync(gcnt, 0, 256 * sizeof(int), stream);
        graph_bounds_kernel<<<cdiv(N, BLK), BLK, 0, stream>>>(batch, gstart, gcnt, N);

        gcn_layer(x0, Q, P, W1, b1, N, F0, F1);
        gcn_layer(P, Q, R, W2, b2, N, F1, F2);
        gcn_layer(R, Q, P, W3, b3, N, F2, F3);

        pool_gather_kernel<<<cdiv(256 * F3, BLK), BLK, 0, stream>>>(P, gstart, gcnt, pool, 256, F3);
        fc(true,  pool, fw1, fb1, fcb, F3, 1024, 1024, 0);
        fc(false, fcb,  fw2, fb2, xc,  1024, 128, 256, out_off);
    };

    branch(pro_x, pro_ei, pro_batch, NP, EP,
           pw1, pb1, 54, 54, pw2, pb2, 108, pw3, pb3, 216,
           pfw1, pfb1, pfw2, pfb2, 128);
    branch(mol_x, mol_ei, mol_batch, NM, EM,
           mw1, mb1, 78, 78, mw2, mb2, 156, mw3, mb3, 312,
           mfw1, mfb1, mfw2, mfb2, 0);

    // combined head
    fc(true, xc,  fc1w, fc1b, hb1, 256, 1024, 1024, 0);
    fc(true, hb1, fc2w, fc2b, hb2, 1024, 512, 512, 0);
    matvec_kernel<<<256, 256, 0, stream>>>(hb2, outw, outb, out, 512);
}

// Round 7
// 952.161 us; speedup vs baseline: 4.1892x; 1.1994x over previous
//
#include <hip/hip_runtime.h>

// DGraphDTA r7: replace graph_bounds atomics (153k contended atomics onto 256
// addrs = 113us, r6's #1) with sorted-batch boundary detection (~256 writes).

static inline int cdiv(int a, int b) { return (a + b - 1) / b; }

// ---------------- CSR build ----------------

__global__ void deg_kernel(const int* __restrict__ dst, int* __restrict__ deg, int E) {
    int t = blockIdx.x * blockDim.x + threadIdx.x;
    if (t < E) atomicAdd(&deg[dst[t]], 1);
}

__global__ void norm_kernel(const int* __restrict__ deg, float* __restrict__ norm, int N) {
    int t = blockIdx.x * blockDim.x + threadIdx.x;
    if (t < N) norm[t] = rsqrtf((float)deg[t] + 1.0f);
}

__global__ void alloc_rows_kernel(const int* __restrict__ deg, int* __restrict__ row_start,
                                  int* __restrict__ fill_cur, int* __restrict__ cursor, int N) {
    int t = blockIdx.x * blockDim.x + threadIdx.x;
    if (t >= N) return;
    int s = atomicAdd(cursor, deg[t]);
    row_start[t] = s;
    fill_cur[t] = s;
}

__global__ void fill_kernel(const int* __restrict__ src, const int* __restrict__ dst,
                            int* __restrict__ fill_cur, int* __restrict__ edge_src, int E) {
    int t = blockIdx.x * blockDim.x + threadIdx.x;
    if (t >= E) return;
    int p = atomicAdd(&fill_cur[dst[t]], 1);
    edge_src[p] = src[t];
}

// ---------------- vectorized gather-aggregate (norm fused) ----------------

__device__ __forceinline__ float4 vmad(float s, float4 a, float4 b) {
    return make_float4(fmaf(s, a.x, b.x), fmaf(s, a.y, b.y), fmaf(s, a.z, b.z), fmaf(s, a.w, b.w));
}
__device__ __forceinline__ float2 vmad(float s, float2 a, float2 b) {
    return make_float2(fmaf(s, a.x, b.x), fmaf(s, a.y, b.y));
}
__device__ __forceinline__ float4 vmul(float s, float4 a) {
    return make_float4(s * a.x, s * a.y, s * a.z, s * a.w);
}
__device__ __forceinline__ float2 vmul(float s, float2 a) {
    return make_float2(s * a.x, s * a.y);
}

template <typename VT>
__global__ __launch_bounds__(256) void gather_agg_kernel(
    const float* __restrict__ x, const float* __restrict__ norm,
    const int* __restrict__ row_start, const int* __restrict__ deg,
    const int* __restrict__ edge_src, float* __restrict__ agg, int N, int Fv)
{
    int t = blockIdx.x * blockDim.x + threadIdx.x;
    if (t >= N * Fv) return;
    int n = t / Fv;
    int jv = t - n * Fv;
    const VT* xv = reinterpret_cast<const VT*>(x);
    VT* aggv = reinterpret_cast<VT*>(agg);

    VT acc = vmul(norm[n], xv[(size_t)n * Fv + jv]);
    int rs = row_start[n];
    int d = deg[n];
    const int* es = edge_src + rs;
    int i = 0;
    for (; i + 2 <= d; i += 2) {
        int s0 = es[i], s1 = es[i + 1];
        float n0 = norm[s0], n1 = norm[s1];
        VT v0 = xv[(size_t)s0 * Fv + jv];
        VT v1 = xv[(size_t)s1 * Fv + jv];
        acc = vmad(n0, v0, acc);
        acc = vmad(n1, v1, acc);
    }
    if (i < d) {
        int s0 = es[i];
        acc = vmad(norm[s0], xv[(size_t)s0 * Fv + jv], acc);
    }
    aggv[t] = acc;
}

// ---------------- tiled GEMM (node-dim: M = 76800 / 10240) ----------------
template <bool RELU, bool SCALE>
__global__ __launch_bounds__(256) void gemm_kernel(
    const float* __restrict__ X, const float* __restrict__ W,
    const float* __restrict__ bias, const float* __restrict__ scale,
    float* __restrict__ out, int M, int K, int N, int out_stride, int out_off)
{
    constexpr int BM = 64, BN = 64, BK = 16, LDA = BM + 4;
    __shared__ __align__(16) float As[BK * LDA];  // As[k][m] (transposed)
    __shared__ __align__(16) float Bs[BK * BN];   // Bs[k][n]
    const int tid = threadIdx.x;
    const int row0 = blockIdx.y * BM, col0 = blockIdx.x * BN;
    const int tx = tid & 15, ty = tid >> 4;

    float acc[4][4] = {};

    const int a_lr = tid >> 4;
    const int a_lk = tid & 15;
    const int b_lc = tid & 63;
    const int b_lk = tid >> 6;

    for (int k0 = 0; k0 < K; k0 += BK) {
#pragma unroll
        for (int p = 0; p < 4; ++p) {
            int r = a_lr + p * 16;
            int gm = row0 + r, gk = k0 + a_lk;
            As[a_lk * LDA + r] = (gm < M && gk < K) ? X[(size_t)gm * K + gk] : 0.0f;
        }
#pragma unroll
        for (int p = 0; p < 4; ++p) {
            int kk = b_lk + p * 4;
            int gk = k0 + kk, gn = col0 + b_lc;
            Bs[kk * BN + b_lc] = (gk < K && gn < N) ? W[(size_t)gk * N + gn] : 0.0f;
        }
        __syncthreads();
#pragma unroll
        for (int k = 0; k < BK; ++k) {
            const float4 a4 = *reinterpret_cast<const float4*>(&As[k * LDA + ty * 4]);
            const float4 b4 = *reinterpret_cast<const float4*>(&Bs[k * BN + tx * 4]);
            const float av[4] = {a4.x, a4.y, a4.z, a4.w};
            const float bv[4] = {b4.x, b4.y, b4.z, b4.w};
#pragma unroll
            for (int i = 0; i < 4; ++i)
#pragma unroll
                for (int j = 0; j < 4; ++j)
                    acc[i][j] = fmaf(av[i], bv[j], acc[i][j]);
        }
        __syncthreads();
    }

#pragma unroll
    for (int i = 0; i < 4; ++i) {
        int gm = row0 + ty * 4 + i;
        if (gm >= M) continue;
        float sc = SCALE ? scale[gm] : 1.0f;
#pragma unroll
        for (int j = 0; j < 4; ++j) {
            int gn = col0 + tx * 4 + j;
            if (gn >= N) continue;
            float v = acc[i][j];
            if (SCALE) v *= sc;
            v += bias[gn];
            if (RELU) v = fmaxf(v, 0.0f);
            out[(size_t)gm * out_stride + out_off + gn] = v;
        }
    }
}

// ---------------- FC kernel (M = 256): split-K + float4 W loads ----------------
template <bool RELU, int JT>
__global__ __launch_bounds__(256) void fc_kernel(
    const float* __restrict__ X, const float* __restrict__ W,
    const float* __restrict__ bias, float* __restrict__ out,
    int K, int N, int out_stride, int out_off)
{
    constexpr int TJ = JT / 4;       // threads along j
    constexpr int SK = 256 / TJ;     // k slices
    extern __shared__ float smem[];  // Xs[K] + red[SK*JT]
    float* Xs = smem;
    float* red = smem + K;

    const int tid = threadIdx.x;
    const int m = blockIdx.y;
    const int j0 = blockIdx.x * JT;

    for (int i = tid; i < K; i += 256) Xs[i] = X[(size_t)m * K + i];
    __syncthreads();

    const int tj = tid % TJ;
    const int s  = tid / TJ;
    const int chunk = (K + SK - 1) / SK;
    const int kb = s * chunk;
    const int ke = min(K, kb + chunk);

    const float4* w4 = reinterpret_cast<const float4*>(W + j0) + tj;
    const int wstride = N >> 2;

    float4 p = make_float4(0.f, 0.f, 0.f, 0.f);
    for (int k = kb; k < ke; ++k) {
        float xk = Xs[k];
        float4 w = w4[(size_t)k * wstride];
        p = vmad(xk, w, p);
    }
    float* rr = red + s * JT + tj * 4;
    rr[0] = p.x; rr[1] = p.y; rr[2] = p.z; rr[3] = p.w;
    __syncthreads();

    if (tid < JT) {
        float v = 0.f;
#pragma unroll
        for (int ss = 0; ss < SK; ++ss) v += red[ss * JT + tid];
        v += bias[j0 + tid];
        if (RELU) v = fmaxf(v, 0.0f);
        out[(size_t)m * out_stride + out_off + j0 + tid] = v;
    }
}

// final layer: one block per row, 256 threads, LDS tree reduce (K=512)
__global__ __launch_bounds__(256) void matvec_kernel(
    const float* __restrict__ X, const float* __restrict__ W,
    const float* __restrict__ bias, float* __restrict__ out, int K)
{
    __shared__ float red[256];
    const int m = blockIdx.x;
    const int tid = threadIdx.x;
    float acc = 0.f;
    for (int k = tid; k < K; k += 256) acc = fmaf(X[(size_t)m * K + k], W[k], acc);
    red[tid] = acc;
    __syncthreads();
    for (int w = 128; w >= 64; w >>= 1) {
        if (tid < w) red[tid] += red[tid + w];
        __syncthreads();
    }
    if (tid < 64) {
        float v = red[tid];
        for (int off = 32; off > 0; off >>= 1) v += __shfl_down(v, off, 64);
        if (tid == 0) out[m] = v + bias[0];
    }
}

// ---------------- pooling: boundary detection on sorted batch ----------------
// gstart[g] = first node index with batch >= g; gstart[B] = N.
// Contention-free: one write per (boundary, covered graph id).
__global__ void graph_starts_kernel(const int* __restrict__ batch, int* __restrict__ gstart,
                                    int N, int B) {
    int t = blockIdx.x * blockDim.x + threadIdx.x;
    if (t >= N) return;
    int b = batch[t];
    int bp = (t == 0) ? -1 : batch[t - 1];
    for (int g = bp + 1; g <= b; ++g) gstart[g] = t;
    if (t == N - 1) {
        for (int g = b + 1; g <= B; ++g) gstart[g] = N;
    }
}

__global__ void pool_gather_kernel(const float* __restrict__ x, const int* __restrict__ gstart,
                                   float* __restrict__ pool, int B, int F) {
    int t = blockIdx.x * blockDim.x + threadIdx.x;
    if (t >= B * F) return;
    int g = t / F;
    int j = t - g * F;
    int s = gstart[g];
    int c = gstart[g + 1] - s;
    float acc = 0.0f;
    for (int i = 0; i < c; ++i) acc += x[(size_t)(s + i) * F + j];
    pool[t] = acc / (float)max(c, 1);
}

extern "C" void kernel_launch(void* const* d_in, const int* in_sizes, int n_in,
                              void* d_out, int out_size, void* d_ws, size_t ws_size,
                              hipStream_t stream) {
    const float* mol_x     = (const float*)d_in[0];
    const int*   mol_ei    = (const int*)  d_in[1];
    const int*   mol_batch = (const int*)  d_in[2];
    const float* pro_x     = (const float*)d_in[3];
    const int*   pro_ei    = (const int*)  d_in[4];
    const int*   pro_batch = (const int*)  d_in[5];
    const float* mw1 = (const float*)d_in[6],  * mb1 = (const float*)d_in[7];
    const float* mw2 = (const float*)d_in[8],  * mb2 = (const float*)d_in[9];
    const float* mw3 = (const float*)d_in[10], * mb3 = (const float*)d_in[11];
    const float* mfw1 = (const float*)d_in[12], * mfb1 = (const float*)d_in[13];
    const float* mfw2 = (const float*)d_in[14], * mfb2 = (const float*)d_in[15];
    const float* pw1 = (const float*)d_in[16], * pb1 = (const float*)d_in[17];
    const float* pw2 = (const float*)d_in[18], * pb2 = (const float*)d_in[19];
    const float* pw3 = (const float*)d_in[20], * pb3 = (const float*)d_in[21];
    const float* pfw1 = (const float*)d_in[22], * pfb1 = (const float*)d_in[23];
    const float* pfw2 = (const float*)d_in[24], * pfb2 = (const float*)d_in[25];
    const float* fc1w = (const float*)d_in[26], * fc1b = (const float*)d_in[27];
    const float* fc2w = (const float*)d_in[28], * fc2b = (const float*)d_in[29];
    const float* outw = (const float*)d_in[30], * outb = (const float*)d_in[31];
    float* out = (float*)d_out;

    // ---- workspace layout ----
    const int NP = 76800, EP = 768000;
    const int NM = 10240, EM = 40960;
    float* P = (float*)d_ws;                  // 76800*216
    float* Q = P + (size_t)NP * 216;          // 76800*108
    float* R = Q + (size_t)NP * 108;          // 76800*108
    float* normb = R + (size_t)NP * 108;      // 76800
    float* pool  = normb + NP;                // 256*312
    float* fcb   = pool + 256 * 312;          // 256*1024
    float* xc    = fcb + 256 * 1024;          // 256*256
    float* hb1   = xc + 256 * 256;            // 256*1024
    float* hb2   = hb1 + 256 * 1024;          // 256*512
    int* deg_i    = (int*)(hb2 + 256 * 512);  // 76800
    int* row_start= deg_i + NP;               // 76800
    int* fill_cur = row_start + NP;           // 76800
    int* edge_src = fill_cur + NP;            // 768000
    int* cursor   = edge_src + EP;            // 64 (pad)
    int* gstart   = cursor + 64;              // 257

    const int BLK = 256;

    auto gcn_layer = [&](const float* xin, float* agg, float* outp,
                         const float* W, const float* b, int N, int Fin, int Fout) {
        if (Fin % 4 == 0) {
            int Fv = Fin / 4;
            gather_agg_kernel<float4><<<cdiv(N * Fv, BLK), BLK, 0, stream>>>(
                xin, normb, row_start, deg_i, edge_src, agg, N, Fv);
        } else {
            int Fv = Fin / 2;
            gather_agg_kernel<float2><<<cdiv(N * Fv, BLK), BLK, 0, stream>>>(
                xin, normb, row_start, deg_i, edge_src, agg, N, Fv);
        }
        dim3 grid(cdiv(Fout, 64), cdiv(N, 64));
        gemm_kernel<true, true><<<grid, 256, 0, stream>>>(agg, W, b, normb, outp, N, Fin, Fout, Fout, 0);
    };

    auto fc = [&](bool relu, const float* X, const float* W, const float* b, float* o,
                  int K, int N, int out_stride, int out_off) {
        size_t lds = (size_t)(K + 1024) * sizeof(float);
        if (N % 256 == 0) {
            dim3 grid(N / 256, 256);
            if (relu) fc_kernel<true, 256><<<grid, 256, lds, stream>>>(X, W, b, o, K, N, out_stride, out_off);
            else      fc_kernel<false, 256><<<grid, 256, lds, stream>>>(X, W, b, o, K, N, out_stride, out_off);
        } else {  // N == 128
            dim3 grid(N / 128, 256);
            if (relu) fc_kernel<true, 128><<<grid, 256, lds, stream>>>(X, W, b, o, K, N, out_stride, out_off);
            else      fc_kernel<false, 128><<<grid, 256, lds, stream>>>(X, W, b, o, K, N, out_stride, out_off);
        }
    };

    auto branch = [&](const float* x0, const int* ei, const int* batch, int N, int E,
                      const float* W1, const float* b1, int F0, int F1,
                      const float* W2, const float* b2, int F2,
                      const float* W3, const float* b3, int F3,
                      const float* fw1, const float* fb1,
                      const float* fw2, const float* fb2, int out_off) {
        // CSR build + norm
        hipMemsetAsync(deg_i, 0, N * sizeof(int), stream);
        hipMemsetAsync(cursor, 0, sizeof(int), stream);
        deg_kernel<<<cdiv(E, BLK), BLK, 0, stream>>>(ei + E, deg_i, E);
        norm_kernel<<<cdiv(N, BLK), BLK, 0, stream>>>(deg_i, normb, N);
        alloc_rows_kernel<<<cdiv(N, BLK), BLK, 0, stream>>>(deg_i, row_start, fill_cur, cursor, N);
        fill_kernel<<<cdiv(E, BLK), BLK, 0, stream>>>(ei, ei + E, fill_cur, edge_src, E);
        // graph ranges for pooling (sorted batch -> boundary detection)
        graph_starts_kernel<<<cdiv(N, BLK), BLK, 0, stream>>>(batch, gstart, N, 256);

        gcn_layer(x0, Q, P, W1, b1, N, F0, F1);
        gcn_layer(P, Q, R, W2, b2, N, F1, F2);
        gcn_layer(R, Q, P, W3, b3, N, F2, F3);

        pool_gather_kernel<<<cdiv(256 * F3, BLK), BLK, 0, stream>>>(P, gstart, pool, 256, F3);
        fc(true,  pool, fw1, fb1, fcb, F3, 1024, 1024, 0);
        fc(false, fcb,  fw2, fb2, xc,  1024, 128, 256, out_off);
    };

    branch(pro_x, pro_ei, pro_batch, NP, EP,
           pw1, pb1, 54, 54, pw2, pb2, 108, pw3, pb3, 216,
           pfw1, pfb1, pfw2, pfb2, 128);
    branch(mol_x, mol_ei, mol_batch, NM, EM,
           mw1, mb1, 78, 78, mw2, mb2, 156, mw3, mb3, 312,
           mfw1, mfb1, mfw2, mfb2, 0);

    // combined head
    fc(true, xc,  fc1w, fc1b, hb1, 256, 1024, 1024, 0);
    fc(true, hb1, fc2w, fc2b, hb2, 1024, 512, 512, 0);
    matvec_kernel<<<256, 256, 0, stream>>>(hb2, outw, outb, out, 512);
}